// Round 9
// baseline (306.553 us; speedup 1.0000x reference)
//
#include <hip/hip_runtime.h>

// B=4, C=256, N=4096 attention modulation.
// out[b,c,i] = newL[b,i]*src[b,c,i] + newB[b,i],
// newL[b,i] = sum_j softmax_j(E)*oldL[j], E = src_i . ref_j over C.
//
// fp16 MFMA 32x32x16 flash, static softmax shift, MFMA-fragment-tiled fp16
// operands, B-tiles via global_load_lds (16B DMA, double-buffered LDS).
// R9 = R7 config (launch_bounds(256,2): proven no-spill, VGPR 116) +
//   (a) accumulator split into 2 independent 8-deep MFMA chains (the 16-deep
//       serial chain through acc was the MFMA-pipe fill limiter at ~2
//       resident blocks/CU; spilling for occupancy (R8) costs 2x),
//   (b) k_reduce+k_modulate merged into k_post (one fewer launch).

#define B_ 4
#define C_ 256
#define N_ 4096
#define LOG2E 1.44269504f
#define SHIFT2 86.5617f      // 60 * log2(e)
#define JSLICE 16
#define BN_ (B_ * N_)
#define NT_ 8                // j-tiles per block (256 j)

typedef _Float16 half_t;
typedef _Float16 v8h  __attribute__((ext_vector_type(8)));
typedef float    v16f __attribute__((ext_vector_type(16)));

#define GLDS16(g, l) __builtin_amdgcn_global_load_lds(                         \
    (const __attribute__((address_space(1))) void*)(g),                        \
    (__attribute__((address_space(3))) void*)(l), 16, 0, 0)

// --------------------------------------------- prep: transpose + old lambda
// z in [0,8): fp32 [B][C][N] -> fp16 fragment-tiled
//   t16[b][tile=n/32][kb=c/16][lane][e], lane=((c>>3)&1)*32+(n&31), e=c&7;
//   src (z<4) additionally scaled by log2(e).
// z == 8: oldL/oldB = 1x1 conv on ref (b = blockIdx.y, n0 = blockIdx.x*64).
__global__ void k_prep(const float* __restrict__ src,
                       const float* __restrict__ ref,
                       const float* __restrict__ wl, const float* __restrict__ bl,
                       const float* __restrict__ wb, const float* __restrict__ bb,
                       half_t* __restrict__ s16, half_t* __restrict__ r16,
                       float* __restrict__ oldL, float* __restrict__ oldB) {
    if (blockIdx.z == 8) {
        int b  = blockIdx.y;
        int n0 = blockIdx.x * 64;
        int nl = threadIdx.x & 63;
        int cq = threadIdx.x >> 6;           // 0..3
        const float* p = ref + ((size_t)b * C_ + cq * 64) * N_ + n0 + nl;
        float aL = 0.f, aB = 0.f;
#pragma unroll 8
        for (int c = 0; c < 64; c++) {
            float v = p[(size_t)c * N_];
            aL += v * wl[cq * 64 + c];
            aB += v * wb[cq * 64 + c];
        }
        __shared__ float red[8][64];
        red[cq][nl]     = aL;
        red[4 + cq][nl] = aB;
        __syncthreads();
        if (threadIdx.x < 64) {
            int t = threadIdx.x;
            oldL[(size_t)b * N_ + n0 + t] =
                red[0][t] + red[1][t] + red[2][t] + red[3][t] + bl[0];
        } else if (threadIdx.x < 128) {
            int t = threadIdx.x - 64;
            oldB[(size_t)b * N_ + n0 + t] =
                red[4][t] + red[5][t] + red[6][t] + red[7][t] + bb[0];
        }
        return;
    }
    __shared__ float tile[64][65];
    int z  = blockIdx.z;
    int b  = z & 3;
    const float* in  = (z < B_) ? src : ref;
    half_t*      out = (z < B_) ? s16 : r16;
    float scale      = (z < B_) ? LOG2E : 1.0f;
    int c0 = blockIdx.y * 64;
    int n0 = blockIdx.x * 64;
    int tx = threadIdx.x & 15, ty = threadIdx.x >> 4;
#pragma unroll
    for (int q = 0; q < 4; q++) {
        int c = ty + q * 16;
        float4 v = *(const float4*)(in + ((size_t)b * C_ + c0 + c) * N_ + n0 + tx * 4);
        tile[c][tx * 4 + 0] = v.x;
        tile[c][tx * 4 + 1] = v.y;
        tile[c][tx * 4 + 2] = v.z;
        tile[c][tx * 4 + 3] = v.w;
    }
    __syncthreads();
    int r   = threadIdx.x & 31;
    int lhi = (threadIdx.x >> 5) & 1;
    int wv  = threadIdx.x >> 6;          // kb_local 0..3
#pragma unroll
    for (int nt = 0; nt < 2; nt++) {
        int nl = nt * 32 + r;
        v8h o;
#pragma unroll
        for (int e = 0; e < 8; e++)
            o[e] = (half_t)(tile[wv * 16 + lhi * 8 + e][nl] * scale);
        size_t tj = (size_t)(n0 >> 5) + nt;
        size_t kb = (size_t)(c0 >> 4) + wv;
        *(v8h*)(out + ((((size_t)b * 128 + tj) * 16 + kb) * 64 + (threadIdx.x & 63)) * 8) = o;
    }
}

// ------------------------------------------------------------------ flash
// grid 2048 = B(4) x jslice(16) x itile(32):
//   b = bid&3 (XCD spread), jslice = (bid>>2)&15, itile = bid>>6.
// block = 256 thr = 4 waves; wave owns 32 i-rows; the 8 B-tiles (16KB)
// staged once per block via global_load_lds into double-buffered LDS.
__global__ __launch_bounds__(256, 2) void k_flash(
        const half_t* __restrict__ sT, const half_t* __restrict__ rT,
        const float* __restrict__ oldL, const float* __restrict__ oldB,
        float* __restrict__ part /* [JSLICE][3][B*N] */) {
    __shared__ half_t lds[2][8192];      // 2 x 16KB
    int bid    = blockIdx.x;
    int b      = bid & 3;
    int jslice = (bid >> 2) & (JSLICE - 1);
    int itile  = bid >> 6;
    int tid    = threadIdx.x;
    int wv     = tid >> 6;
    int lane   = tid & 63;
    int l31    = lane & 31, lhi = lane >> 5;
    int ti     = itile * 4 + wv;          // 32-row A tile index
    int i0     = ti * 32;
    int j0     = jslice * (N_ / JSLICE);  // 256 j per block
    int tj0    = j0 >> 5;

    // A fragments: one coalesced 1KB load per kb, held in VGPRs all kernel.
    const half_t* aP = sT + (((size_t)b * 128 + ti) * 16) * 512 + (size_t)lane * 8;
    v8h a[16];
#pragma unroll
    for (int kb = 0; kb < 16; kb++) a[kb] = *(const v8h*)(aP + (size_t)kb * 512);

    const half_t* bBase = rT + (((size_t)b * 128 + tj0) * 16) * 512;  // block-uniform
    const float*  oLp = oldL + (size_t)b * N_ + j0 + l31;
    const float*  oBp = oldB + (size_t)b * N_ + j0 + l31;

    float sp[16], sl[16], sb[16];
#pragma unroll
    for (int r = 0; r < 16; r++) { sp[r] = 0.f; sl[r] = 0.f; sb[r] = 0.f; }

    // Prologue: DMA tile 0 into buffer 0. Wave wv covers chunks (q*4+wv)*1KB.
#pragma unroll
    for (int q = 0; q < 4; q++) {
        int chunk = q * 4 + wv;
        GLDS16(bBase + (size_t)chunk * 512 + (size_t)lane * 8,
               &lds[0][(size_t)chunk * 512]);
    }

    for (int jt = 0; jt < NT_; jt++) {
        __syncthreads();                       // drains DMA -> buf[jt&1] ready
        if (jt + 1 < NT_) {                    // DMA next tile into other buffer
            const half_t* g = bBase + (size_t)(jt + 1) * 8192;
#pragma unroll
            for (int q = 0; q < 4; q++) {
                int chunk = q * 4 + wv;
                GLDS16(g + (size_t)chunk * 512 + (size_t)lane * 8,
                       &lds[(jt + 1) & 1][(size_t)chunk * 512]);
            }
        }
        const half_t* bt = lds[jt & 1] + (size_t)lane * 8;
        // Two independent 8-deep MFMA chains (ILP for the MFMA pipe).
        v16f acc0, acc1;
#pragma unroll
        for (int r = 0; r < 16; r++) { acc0[r] = -SHIFT2; acc1[r] = 0.f; }
#pragma unroll
        for (int kb = 0; kb < 8; kb++) {
            acc0 = __builtin_amdgcn_mfma_f32_32x32x16_f16(
                a[kb],     *(const v8h*)(bt + (size_t)kb * 512),       acc0, 0, 0, 0);
            acc1 = __builtin_amdgcn_mfma_f32_32x32x16_f16(
                a[kb + 8], *(const v8h*)(bt + (size_t)(kb + 8) * 512), acc1, 0, 0, 0);
        }
        float lam = oLp[jt * 32], bet = oBp[jt * 32];
#pragma unroll
        for (int r = 0; r < 16; r++) {
            float p = __builtin_amdgcn_exp2f(acc0[r] + acc1[r]);
            sp[r] += p;
            sl[r] += p * lam;
            sb[r] += p * bet;
        }
    }

    float* pSP = part + ((size_t)jslice * 3 + 0) * BN_;
    float* pSL = part + ((size_t)jslice * 3 + 1) * BN_;
    float* pSB = part + ((size_t)jslice * 3 + 2) * BN_;
#pragma unroll
    for (int r = 0; r < 16; r++) {
        float tp = sp[r], tl = sl[r], tb = sb[r];
#pragma unroll
        for (int m = 1; m <= 16; m <<= 1) {
            tp += __shfl_xor(tp, m, 64);
            tl += __shfl_xor(tl, m, 64);
            tb += __shfl_xor(tb, m, 64);
        }
        if (l31 == 0) {
            // C/D layout: row = (reg&3) + 8*(reg>>2) + 4*(lane>>5)
            int row = (r & 3) + 8 * (r >> 2) + 4 * lhi;
            size_t ig = (size_t)b * N_ + i0 + row;
            pSP[ig] = tp; pSL[ig] = tl; pSB[ig] = tb;
        }
    }
}

// ------------------------- epilogue: combine partials + modulate (fused)
// grid (B, N/256, C/64); block 256. Each block computes newL/newB for its
// 256 pixels once (in LDS), then sweeps 64 channels with coalesced 1KB
// loads/stores.
__global__ void k_post(const float* __restrict__ src,
                       const float* __restrict__ part,
                       float* __restrict__ out) {
    __shared__ float sL[256], sB[256];
    int b  = blockIdx.x;
    int n0 = blockIdx.y * 256;
    int c0 = blockIdx.z * 64;
    int t  = threadIdx.x;
    size_t bn = (size_t)b * N_ + n0 + t;
    float sp = 0.f, sl = 0.f, sb = 0.f;
#pragma unroll
    for (int s = 0; s < JSLICE; s++) {
        sp += part[((size_t)s * 3 + 0) * BN_ + bn];
        sl += part[((size_t)s * 3 + 1) * BN_ + bn];
        sb += part[((size_t)s * 3 + 2) * BN_ + bn];
    }
    float inv = 1.0f / sp;
    sL[t] = sl * inv;
    sB[t] = sb * inv;
    __syncthreads();
    int nl = t & 255;   // pixel within chunk (t itself), but re-read via LDS
    const float* sp0 = src + ((size_t)b * C_ + c0) * N_ + n0;
    float*       op0 = out + ((size_t)b * C_ + c0) * N_ + n0;
#pragma unroll 4
    for (int c = 0; c < 64; c++) {
        float v = sp0[(size_t)c * N_ + nl];
        op0[(size_t)c * N_ + nl] = sL[nl] * v + sB[nl];
    }
}

extern "C" void kernel_launch(void* const* d_in, const int* in_sizes, int n_in,
                              void* d_out, int out_size, void* d_ws, size_t ws_size,
                              hipStream_t stream) {
    const float* src = (const float*)d_in[0];
    const float* ref = (const float*)d_in[1];
    const float* wl  = (const float*)d_in[2];
    const float* bl  = (const float*)d_in[3];
    const float* wb  = (const float*)d_in[4];
    const float* bb  = (const float*)d_in[5];
    float* out = (float*)d_out;

    float* oldL = (float*)d_ws;
    float* oldB = oldL + BN_;
    float* part = oldB + BN_;
    size_t needF  = ((size_t)2 + 3 * JSLICE) * BN_ * sizeof(float);
    size_t need16 = (size_t)2 * B_ * N_ * C_ * sizeof(half_t);
    half_t* s16;
    if (ws_size >= needF + need16) s16 = (half_t*)((char*)d_ws + needF);
    else                           s16 = (half_t*)d_out;   // overwritten by k_post
    half_t* r16 = s16 + (size_t)B_ * N_ * C_;

    k_prep<<<dim3(N_ / 64, C_ / 64, 9), 256, 0, stream>>>(
        src, ref, wl, bl, wb, bb, s16, r16, oldL, oldB);
    k_flash<<<2048, 256, 0, stream>>>(s16, r16, oldL, oldB, part);
    k_post<<<dim3(B_, N_ / 256, C_ / 64), 256, 0, stream>>>(src, part, out);
}

// Round 10
// 148.577 us; speedup vs baseline: 2.0633x; 2.0633x over previous
//
#include <hip/hip_runtime.h>

// B=4, C=256, N=4096 attention modulation.
// out[b,c,i] = newL[b,i]*src[b,c,i] + newB[b,i],
// newL[b,i] = sum_j softmax_j(E)*oldL[j], E = src_i . ref_j over C.
//
// fp16 MFMA 32x32x16 flash, static softmax shift, MFMA-fragment-tiled fp16
// operands, B-tiles via global_load_lds (16B DMA, double-buffered LDS).
// R10 = byte-exact R7 flash (the only proven no-spill config: VGPR 116,
// launch_bounds(256,2), single 16-deep MFMA chain -- R8's (256,4) and R9's
// 2-chain split BOTH spilled to scratch, 200+MB FETCH) + R9's fused k_post
// epilogue (reduce+modulate in one launch).

#define B_ 4
#define C_ 256
#define N_ 4096
#define LOG2E 1.44269504f
#define SHIFT2 86.5617f      // 60 * log2(e)
#define JSLICE 16
#define BN_ (B_ * N_)
#define NT_ 8                // j-tiles per block (256 j)

typedef _Float16 half_t;
typedef _Float16 v8h  __attribute__((ext_vector_type(8)));
typedef float    v16f __attribute__((ext_vector_type(16)));

#define GLDS16(g, l) __builtin_amdgcn_global_load_lds(                         \
    (const __attribute__((address_space(1))) void*)(g),                        \
    (__attribute__((address_space(3))) void*)(l), 16, 0, 0)

// --------------------------------------------- prep: transpose + old lambda
// z in [0,8): fp32 [B][C][N] -> fp16 fragment-tiled
//   t16[b][tile=n/32][kb=c/16][lane][e], lane=((c>>3)&1)*32+(n&31), e=c&7;
//   src (z<4) additionally scaled by log2(e).
// z == 8: oldL/oldB = 1x1 conv on ref (b = blockIdx.y, n0 = blockIdx.x*64).
__global__ void k_prep(const float* __restrict__ src,
                       const float* __restrict__ ref,
                       const float* __restrict__ wl, const float* __restrict__ bl,
                       const float* __restrict__ wb, const float* __restrict__ bb,
                       half_t* __restrict__ s16, half_t* __restrict__ r16,
                       float* __restrict__ oldL, float* __restrict__ oldB) {
    if (blockIdx.z == 8) {
        int b  = blockIdx.y;
        int n0 = blockIdx.x * 64;
        int nl = threadIdx.x & 63;
        int cq = threadIdx.x >> 6;           // 0..3
        const float* p = ref + ((size_t)b * C_ + cq * 64) * N_ + n0 + nl;
        float aL = 0.f, aB = 0.f;
#pragma unroll 8
        for (int c = 0; c < 64; c++) {
            float v = p[(size_t)c * N_];
            aL += v * wl[cq * 64 + c];
            aB += v * wb[cq * 64 + c];
        }
        __shared__ float red[8][64];
        red[cq][nl]     = aL;
        red[4 + cq][nl] = aB;
        __syncthreads();
        if (threadIdx.x < 64) {
            int t = threadIdx.x;
            oldL[(size_t)b * N_ + n0 + t] =
                red[0][t] + red[1][t] + red[2][t] + red[3][t] + bl[0];
        } else if (threadIdx.x < 128) {
            int t = threadIdx.x - 64;
            oldB[(size_t)b * N_ + n0 + t] =
                red[4][t] + red[5][t] + red[6][t] + red[7][t] + bb[0];
        }
        return;
    }
    __shared__ float tile[64][65];
    int z  = blockIdx.z;
    int b  = z & 3;
    const float* in  = (z < B_) ? src : ref;
    half_t*      out = (z < B_) ? s16 : r16;
    float scale      = (z < B_) ? LOG2E : 1.0f;
    int c0 = blockIdx.y * 64;
    int n0 = blockIdx.x * 64;
    int tx = threadIdx.x & 15, ty = threadIdx.x >> 4;
#pragma unroll
    for (int q = 0; q < 4; q++) {
        int c = ty + q * 16;
        float4 v = *(const float4*)(in + ((size_t)b * C_ + c0 + c) * N_ + n0 + tx * 4);
        tile[c][tx * 4 + 0] = v.x;
        tile[c][tx * 4 + 1] = v.y;
        tile[c][tx * 4 + 2] = v.z;
        tile[c][tx * 4 + 3] = v.w;
    }
    __syncthreads();
    int r   = threadIdx.x & 31;
    int lhi = (threadIdx.x >> 5) & 1;
    int wv  = threadIdx.x >> 6;          // kb_local 0..3
#pragma unroll
    for (int nt = 0; nt < 2; nt++) {
        int nl = nt * 32 + r;
        v8h o;
#pragma unroll
        for (int e = 0; e < 8; e++)
            o[e] = (half_t)(tile[wv * 16 + lhi * 8 + e][nl] * scale);
        size_t tj = (size_t)(n0 >> 5) + nt;
        size_t kb = (size_t)(c0 >> 4) + wv;
        *(v8h*)(out + ((((size_t)b * 128 + tj) * 16 + kb) * 64 + (threadIdx.x & 63)) * 8) = o;
    }
}

// ------------------------------------------------------------------ flash
// grid 2048 = B(4) x jslice(16) x itile(32):
//   b = bid&3 (XCD spread), jslice = (bid>>2)&15, itile = bid>>6.
// block = 256 thr = 4 waves; wave owns 32 i-rows; the 8 B-tiles (16KB) are
// staged once per block via global_load_lds (dwordx4) into double-buffered
// LDS and shared by all 4 waves. Prefetch for jt+1 issues right after the
// barrier; the next barrier's vmcnt drain guarantees completion.
__global__ __launch_bounds__(256, 2) void k_flash(
        const half_t* __restrict__ sT, const half_t* __restrict__ rT,
        const float* __restrict__ oldL, const float* __restrict__ oldB,
        float* __restrict__ part /* [JSLICE][3][B*N] */) {
    __shared__ half_t lds[2][8192];      // 2 x 16KB
    int bid    = blockIdx.x;
    int b      = bid & 3;
    int jslice = (bid >> 2) & (JSLICE - 1);
    int itile  = bid >> 6;
    int tid    = threadIdx.x;
    int wv     = tid >> 6;
    int lane   = tid & 63;
    int l31    = lane & 31, lhi = lane >> 5;
    int ti     = itile * 4 + wv;          // 32-row A tile index
    int i0     = ti * 32;
    int j0     = jslice * (N_ / JSLICE);  // 256 j per block
    int tj0    = j0 >> 5;

    // A fragments: one coalesced 1KB load per kb, held in VGPRs all kernel.
    const half_t* aP = sT + (((size_t)b * 128 + ti) * 16) * 512 + (size_t)lane * 8;
    v8h a[16];
#pragma unroll
    for (int kb = 0; kb < 16; kb++) a[kb] = *(const v8h*)(aP + (size_t)kb * 512);

    const half_t* bBase = rT + (((size_t)b * 128 + tj0) * 16) * 512;  // block-uniform
    const float*  oLp = oldL + (size_t)b * N_ + j0 + l31;
    const float*  oBp = oldB + (size_t)b * N_ + j0 + l31;

    float sp[16], sl[16], sb[16];
#pragma unroll
    for (int r = 0; r < 16; r++) { sp[r] = 0.f; sl[r] = 0.f; sb[r] = 0.f; }

    // Prologue: DMA tile 0 into buffer 0. Wave wv covers chunks (q*4+wv)*1KB.
#pragma unroll
    for (int q = 0; q < 4; q++) {
        int chunk = q * 4 + wv;
        GLDS16(bBase + (size_t)chunk * 512 + (size_t)lane * 8,
               &lds[0][(size_t)chunk * 512]);
    }

    for (int jt = 0; jt < NT_; jt++) {
        __syncthreads();                       // drains DMA -> buf[jt&1] ready
        if (jt + 1 < NT_) {                    // DMA next tile into other buffer
            const half_t* g = bBase + (size_t)(jt + 1) * 8192;
#pragma unroll
            for (int q = 0; q < 4; q++) {
                int chunk = q * 4 + wv;
                GLDS16(g + (size_t)chunk * 512 + (size_t)lane * 8,
                       &lds[(jt + 1) & 1][(size_t)chunk * 512]);
            }
        }
        const half_t* bt = lds[jt & 1] + (size_t)lane * 8;
        v16f acc;
#pragma unroll
        for (int r = 0; r < 16; r++) acc[r] = -SHIFT2;
#pragma unroll
        for (int kb = 0; kb < 16; kb++) {
            v8h bf = *(const v8h*)(bt + (size_t)kb * 512);
            acc = __builtin_amdgcn_mfma_f32_32x32x16_f16(a[kb], bf, acc, 0, 0, 0);
        }
        float lam = oLp[jt * 32], bet = oBp[jt * 32];
#pragma unroll
        for (int r = 0; r < 16; r++) {
            float p = __builtin_amdgcn_exp2f(acc[r]);
            sp[r] += p;
            sl[r] += p * lam;
            sb[r] += p * bet;
        }
    }

    float* pSP = part + ((size_t)jslice * 3 + 0) * BN_;
    float* pSL = part + ((size_t)jslice * 3 + 1) * BN_;
    float* pSB = part + ((size_t)jslice * 3 + 2) * BN_;
#pragma unroll
    for (int r = 0; r < 16; r++) {
        float tp = sp[r], tl = sl[r], tb = sb[r];
#pragma unroll
        for (int m = 1; m <= 16; m <<= 1) {
            tp += __shfl_xor(tp, m, 64);
            tl += __shfl_xor(tl, m, 64);
            tb += __shfl_xor(tb, m, 64);
        }
        if (l31 == 0) {
            // C/D layout: row = (reg&3) + 8*(reg>>2) + 4*(lane>>5)
            int row = (r & 3) + 8 * (r >> 2) + 4 * lhi;
            size_t ig = (size_t)b * N_ + i0 + row;
            pSP[ig] = tp; pSL[ig] = tl; pSB[ig] = tb;
        }
    }
}

// ------------------------- epilogue: combine partials + modulate (fused)
// grid (B, N/256, C/64); block 256. Each block computes newL/newB for its
// 256 pixels once (in LDS), then sweeps 64 channels with coalesced loads.
__global__ void k_post(const float* __restrict__ src,
                       const float* __restrict__ part,
                       float* __restrict__ out) {
    __shared__ float sL[256], sB[256];
    int b  = blockIdx.x;
    int n0 = blockIdx.y * 256;
    int c0 = blockIdx.z * 64;
    int t  = threadIdx.x;
    size_t bn = (size_t)b * N_ + n0 + t;
    float sp = 0.f, sl = 0.f, sb = 0.f;
#pragma unroll
    for (int s = 0; s < JSLICE; s++) {
        sp += part[((size_t)s * 3 + 0) * BN_ + bn];
        sl += part[((size_t)s * 3 + 1) * BN_ + bn];
        sb += part[((size_t)s * 3 + 2) * BN_ + bn];
    }
    float inv = 1.0f / sp;
    sL[t] = sl * inv;
    sB[t] = sb * inv;
    __syncthreads();
    const float* sp0 = src + ((size_t)b * C_ + c0) * N_ + n0;
    float*       op0 = out + ((size_t)b * C_ + c0) * N_ + n0;
#pragma unroll 4
    for (int c = 0; c < 64; c++) {
        float v = sp0[(size_t)c * N_ + t];
        op0[(size_t)c * N_ + t] = sL[t] * v + sB[t];
    }
}

extern "C" void kernel_launch(void* const* d_in, const int* in_sizes, int n_in,
                              void* d_out, int out_size, void* d_ws, size_t ws_size,
                              hipStream_t stream) {
    const float* src = (const float*)d_in[0];
    const float* ref = (const float*)d_in[1];
    const float* wl  = (const float*)d_in[2];
    const float* bl  = (const float*)d_in[3];
    const float* wb  = (const float*)d_in[4];
    const float* bb  = (const float*)d_in[5];
    float* out = (float*)d_out;

    float* oldL = (float*)d_ws;
    float* oldB = oldL + BN_;
    float* part = oldB + BN_;
    size_t needF  = ((size_t)2 + 3 * JSLICE) * BN_ * sizeof(float);
    size_t need16 = (size_t)2 * B_ * N_ * C_ * sizeof(half_t);
    half_t* s16;
    if (ws_size >= needF + need16) s16 = (half_t*)((char*)d_ws + needF);
    else                           s16 = (half_t*)d_out;   // overwritten by k_post
    half_t* r16 = s16 + (size_t)B_ * N_ * C_;

    k_prep<<<dim3(N_ / 64, C_ / 64, 9), 256, 0, stream>>>(
        src, ref, wl, bl, wb, bb, s16, r16, oldL, oldB);
    k_flash<<<2048, 256, 0, stream>>>(s16, r16, oldL, oldB, part);
    k_post<<<dim3(B_, N_ / 256, C_ / 64), 256, 0, stream>>>(src, part, out);
}

// Round 11
// 146.758 us; speedup vs baseline: 2.0888x; 1.0124x over previous
//
#include <hip/hip_runtime.h>

// B=4, C=256, N=4096 attention modulation.
// out[b,c,i] = newL[b,i]*src[b,c,i] + newB[b,i],
// newL[b,i] = sum_j softmax_j(E)*oldL[j], E = src_i . ref_j over C.
//
// fp16 MFMA 32x32x16 flash, static softmax shift, MFMA-fragment-tiled fp16
// operands, B-tiles via global_load_lds (16B DMA, double-buffered LDS).
// R11: (a) flash blocks widened to 512 thr / 8 waves sharing one B-tile --
// per-thread code identical to the proven no-spill R7 config (VGPR 116),
// doubling resident waves/CU (16 vs 8) for pipe overlap; grid 512 = one
// generation. (b) k_prep transpose retiled to 256n x 16c so every global
// access is 1KB/wave contiguous. (c) k_post: thread owns 4 consecutive
// pixels, newL/newB in registers, 4KB-contiguous channel sweep.

#define B_ 4
#define C_ 256
#define N_ 4096
#define LOG2E 1.44269504f
#define SHIFT2 86.5617f      // 60 * log2(e)
#define JSLICE 8
#define BN_ (B_ * N_)
#define NT_ 16               // j-tiles per block (512 j)

typedef _Float16 half_t;
typedef _Float16 v8h  __attribute__((ext_vector_type(8)));
typedef float    v16f __attribute__((ext_vector_type(16)));

#define GLDS16(g, l) __builtin_amdgcn_global_load_lds(                         \
    (const __attribute__((address_space(1))) void*)(g),                        \
    (__attribute__((address_space(3))) void*)(l), 16, 0, 0)

// --------------------------------------------- prep: transpose + old lambda
// grid (N/256=16, C/16=16, 9), block 256.
// z in [0,8): fp32 [B][C][N] -> fp16 fragment-tiled
//   t16[b][tile=n/32][kb=c/16][lane][e], lane=((c>>3)&1)*32+(n&31), e=c&7;
//   src (z<4) additionally scaled by log2(e). 256x16 tile: reads are 1KB
//   rows (64 lanes x float4), writes are 1KB v8h runs.
// z == 8: oldL/oldB 1x1 conv on ref; flat block id -> (b, n-block).
__global__ void k_prep(const float* __restrict__ src,
                       const float* __restrict__ ref,
                       const float* __restrict__ wl, const float* __restrict__ bl,
                       const float* __restrict__ wb, const float* __restrict__ bb,
                       half_t* __restrict__ s16, half_t* __restrict__ r16,
                       float* __restrict__ oldL, float* __restrict__ oldB) {
    if (blockIdx.z == 8) {
        int flat = blockIdx.y * 16 + blockIdx.x;   // 0..255
        int b  = flat & 3;
        int n0 = (flat >> 2) * 64;
        int nl = threadIdx.x & 63;
        int cq = threadIdx.x >> 6;           // 0..3
        const float* p = ref + ((size_t)b * C_ + cq * 64) * N_ + n0 + nl;
        float aL = 0.f, aB = 0.f;
#pragma unroll 8
        for (int c = 0; c < 64; c++) {
            float v = p[(size_t)c * N_];
            aL += v * wl[cq * 64 + c];
            aB += v * wb[cq * 64 + c];
        }
        __shared__ float red[8][64];
        red[cq][nl]     = aL;
        red[4 + cq][nl] = aB;
        __syncthreads();
        if (threadIdx.x < 64) {
            int t = threadIdx.x;
            oldL[(size_t)b * N_ + n0 + t] =
                red[0][t] + red[1][t] + red[2][t] + red[3][t] + bl[0];
        } else if (threadIdx.x < 128) {
            int t = threadIdx.x - 64;
            oldB[(size_t)b * N_ + n0 + t] =
                red[4][t] + red[5][t] + red[6][t] + red[7][t] + bb[0];
        }
        return;
    }
    __shared__ float tile[16][257];
    int z  = blockIdx.z;
    int b  = z & 3;
    const float* in  = (z < B_) ? src : ref;
    half_t*      out = (z < B_) ? s16 : r16;
    float scale      = (z < B_) ? LOG2E : 1.0f;
    int n0 = blockIdx.x * 256;
    int c0 = blockIdx.y * 16;
    int t    = threadIdx.x;
    int lane = t & 63;
    int wvid = t >> 6;                   // 0..3
    // Read: 16 c-rows, each 256 floats = 1KB per wave (64 lanes x float4).
#pragma unroll
    for (int p = 0; p < 4; p++) {
        int c = p * 4 + wvid;
        float4 v = *(const float4*)(in + ((size_t)b * C_ + c0 + c) * N_ + n0 + lane * 4);
        tile[c][lane * 4 + 0] = v.x;
        tile[c][lane * 4 + 1] = v.y;
        tile[c][lane * 4 + 2] = v.z;
        tile[c][lane * 4 + 3] = v.w;
    }
    __syncthreads();
    // Write: 8 n-tiles x 1 kb; per (tile) one 1KB contiguous v8h run/wave.
    int l31 = lane & 31, lhi = lane >> 5;
    size_t kb = (size_t)(c0 >> 4);
#pragma unroll
    for (int p = 0; p < 2; p++) {
        int tjl = p * 4 + wvid;          // 0..7
        v8h o;
#pragma unroll
        for (int e = 0; e < 8; e++)
            o[e] = (half_t)(tile[lhi * 8 + e][tjl * 32 + l31] * scale);
        size_t tj = (size_t)(n0 >> 5) + tjl;
        *(v8h*)(out + ((((size_t)b * 128 + tj) * 16 + kb) * 64 + lane) * 8) = o;
    }
}

// ------------------------------------------------------------------ flash
// grid 512 = B(4) x jslice(8) x iblock(16):
//   b = bid&3 (XCD spread), jslice = (bid>>2)&7, iblock = bid>>5.
// block = 512 thr = 8 waves; wave owns 32 i-rows (256 rows/block); the 16
// B-tiles (16KB each) staged once per block via global_load_lds into
// double-buffered LDS, shared by all 8 waves. Per-thread register use is
// identical to the proven R7 config (VGPR 116, no spill).
__global__ __launch_bounds__(512, 2) void k_flash(
        const half_t* __restrict__ sT, const half_t* __restrict__ rT,
        const float* __restrict__ oldL, const float* __restrict__ oldB,
        float* __restrict__ part /* [JSLICE][3][B*N] */) {
    __shared__ half_t lds[2][8192];      // 2 x 16KB
    int bid    = blockIdx.x;
    int b      = bid & 3;
    int jslice = (bid >> 2) & (JSLICE - 1);
    int iblock = bid >> 5;
    int tid    = threadIdx.x;
    int wv     = tid >> 6;               // 0..7
    int lane   = tid & 63;
    int l31    = lane & 31, lhi = lane >> 5;
    int ti     = iblock * 8 + wv;        // 32-row A tile index
    int i0     = ti * 32;
    int j0     = jslice * (N_ / JSLICE); // 512 j per block
    int tj0    = j0 >> 5;

    // A fragments: one coalesced 1KB load per kb, held in VGPRs all kernel.
    const half_t* aP = sT + (((size_t)b * 128 + ti) * 16) * 512 + (size_t)lane * 8;
    v8h a[16];
#pragma unroll
    for (int kb = 0; kb < 16; kb++) a[kb] = *(const v8h*)(aP + (size_t)kb * 512);

    const half_t* bBase = rT + (((size_t)b * 128 + tj0) * 16) * 512;  // block-uniform
    const float*  oLp = oldL + (size_t)b * N_ + j0 + l31;
    const float*  oBp = oldB + (size_t)b * N_ + j0 + l31;

    float sp[16], sl[16], sb[16];
#pragma unroll
    for (int r = 0; r < 16; r++) { sp[r] = 0.f; sl[r] = 0.f; sb[r] = 0.f; }

    // Prologue: DMA tile 0 into buffer 0. Wave wv covers chunks {wv, wv+8}.
#pragma unroll
    for (int q = 0; q < 2; q++) {
        int chunk = q * 8 + wv;
        GLDS16(bBase + (size_t)chunk * 512 + (size_t)lane * 8,
               &lds[0][(size_t)chunk * 512]);
    }

    for (int jt = 0; jt < NT_; jt++) {
        __syncthreads();                       // drains DMA -> buf[jt&1] ready
        if (jt + 1 < NT_) {                    // DMA next tile into other buffer
            const half_t* g = bBase + (size_t)(jt + 1) * 8192;
#pragma unroll
            for (int q = 0; q < 2; q++) {
                int chunk = q * 8 + wv;
                GLDS16(g + (size_t)chunk * 512 + (size_t)lane * 8,
                       &lds[(jt + 1) & 1][(size_t)chunk * 512]);
            }
        }
        const half_t* bt = lds[jt & 1] + (size_t)lane * 8;
        v16f acc;
#pragma unroll
        for (int r = 0; r < 16; r++) acc[r] = -SHIFT2;
#pragma unroll
        for (int kb = 0; kb < 16; kb++) {
            v8h bf = *(const v8h*)(bt + (size_t)kb * 512);
            acc = __builtin_amdgcn_mfma_f32_32x32x16_f16(a[kb], bf, acc, 0, 0, 0);
        }
        float lam = oLp[jt * 32], bet = oBp[jt * 32];
#pragma unroll
        for (int r = 0; r < 16; r++) {
            float p = __builtin_amdgcn_exp2f(acc[r]);
            sp[r] += p;
            sl[r] += p * lam;
            sb[r] += p * bet;
        }
    }

    float* pSP = part + ((size_t)jslice * 3 + 0) * BN_;
    float* pSL = part + ((size_t)jslice * 3 + 1) * BN_;
    float* pSB = part + ((size_t)jslice * 3 + 2) * BN_;
#pragma unroll
    for (int r = 0; r < 16; r++) {
        float tp = sp[r], tl = sl[r], tb = sb[r];
#pragma unroll
        for (int m = 1; m <= 16; m <<= 1) {
            tp += __shfl_xor(tp, m, 64);
            tl += __shfl_xor(tl, m, 64);
            tb += __shfl_xor(tb, m, 64);
        }
        if (l31 == 0) {
            // C/D layout: row = (reg&3) + 8*(reg>>2) + 4*(lane>>5)
            int row = (r & 3) + 8 * (r >> 2) + 4 * lhi;
            size_t ig = (size_t)b * N_ + i0 + row;
            pSP[ig] = tp; pSL[ig] = tl; pSB[ig] = tb;
        }
    }
}

// ------------------------- epilogue: combine partials + modulate (fused)
// grid (B, N/1024, C/16), block 256. Thread owns 4 consecutive pixels:
// newL/newB computed once into registers, then a 16-channel sweep with
// 4KB-contiguous float4 lines.
__global__ void k_post(const float* __restrict__ src,
                       const float* __restrict__ part,
                       float* __restrict__ out) {
    int b  = blockIdx.x;
    int n0 = blockIdx.y * 1024;
    int c0 = blockIdx.z * 16;
    int t  = threadIdx.x;
    size_t bn = (size_t)b * N_ + n0 + t * 4;
    float4 sp = {0.f, 0.f, 0.f, 0.f}, sl = sp, sb = sp;
#pragma unroll
    for (int s = 0; s < JSLICE; s++) {
        float4 p0 = *(const float4*)(part + ((size_t)s * 3 + 0) * BN_ + bn);
        float4 p1 = *(const float4*)(part + ((size_t)s * 3 + 1) * BN_ + bn);
        float4 p2 = *(const float4*)(part + ((size_t)s * 3 + 2) * BN_ + bn);
        sp.x += p0.x; sp.y += p0.y; sp.z += p0.z; sp.w += p0.w;
        sl.x += p1.x; sl.y += p1.y; sl.z += p1.z; sl.w += p1.w;
        sb.x += p2.x; sb.y += p2.y; sb.z += p2.z; sb.w += p2.w;
    }
    float4 L, T;
    L.x = sl.x / sp.x; L.y = sl.y / sp.y; L.z = sl.z / sp.z; L.w = sl.w / sp.w;
    T.x = sb.x / sp.x; T.y = sb.y / sp.y; T.z = sb.z / sp.z; T.w = sb.w / sp.w;
    const float* sp0 = src + ((size_t)b * C_ + c0) * N_ + n0 + t * 4;
    float*       op0 = out + ((size_t)b * C_ + c0) * N_ + n0 + t * 4;
#pragma unroll 4
    for (int c = 0; c < 16; c++) {
        float4 v = *(const float4*)(sp0 + (size_t)c * N_);
        float4 o;
        o.x = L.x * v.x + T.x;
        o.y = L.y * v.y + T.y;
        o.z = L.z * v.z + T.z;
        o.w = L.w * v.w + T.w;
        *(float4*)(op0 + (size_t)c * N_) = o;
    }
}

extern "C" void kernel_launch(void* const* d_in, const int* in_sizes, int n_in,
                              void* d_out, int out_size, void* d_ws, size_t ws_size,
                              hipStream_t stream) {
    const float* src = (const float*)d_in[0];
    const float* ref = (const float*)d_in[1];
    const float* wl  = (const float*)d_in[2];
    const float* bl  = (const float*)d_in[3];
    const float* wb  = (const float*)d_in[4];
    const float* bb  = (const float*)d_in[5];
    float* out = (float*)d_out;

    float* oldL = (float*)d_ws;
    float* oldB = oldL + BN_;
    float* part = oldB + BN_;
    size_t needF  = ((size_t)2 + 3 * JSLICE) * BN_ * sizeof(float);
    size_t need16 = (size_t)2 * B_ * N_ * C_ * sizeof(half_t);
    half_t* s16;
    if (ws_size >= needF + need16) s16 = (half_t*)((char*)d_ws + needF);
    else                           s16 = (half_t*)d_out;   // overwritten by k_post
    half_t* r16 = s16 + (size_t)B_ * N_ * C_;

    k_prep<<<dim3(N_ / 256, C_ / 16, 9), 256, 0, stream>>>(
        src, ref, wl, bl, wb, bb, s16, r16, oldL, oldB);
    k_flash<<<512, 512, 0, stream>>>(s16, r16, oldL, oldB, part);
    k_post<<<dim3(B_, N_ / 1024, C_ / 16), 256, 0, stream>>>(src, part, out);
}

// Round 12
// 143.218 us; speedup vs baseline: 2.1405x; 1.0247x over previous
//
#include <hip/hip_runtime.h>

// B=4, C=256, N=4096 attention modulation.
// out[b,c,i] = newL[b,i]*src[b,c,i] + newB[b,i],
// newL[b,i] = sum_j softmax_j(E)*oldL[j], E = src_i . ref_j over C.
//
// fp16 MFMA 32x32x16 flash, static softmax shift, MFMA-fragment-tiled fp16
// operands, B-tiles via global_load_lds (16B DMA, double-buffered LDS),
// 512-thr blocks (8 waves share each B-tile).
// R12: (a) dual independent 8-deep MFMA chains -- R11's single 16-deep
// chain serialized the pipes (sum-not-max cycle accounting); the 512-thr
// kernel's VGPR base is 88 (vs 116 at 256-thr), so +16 regs now fits
// without spill (R9's spill was on the 116 base). (b) prep reverted to the
// R10 64x65 tiling (R11's stride-4 LDS writes = 8-way bank conflicts,
// remainder 85.7 -> 97.9 us). (c) post kept from R11 (float4).

#define B_ 4
#define C_ 256
#define N_ 4096
#define LOG2E 1.44269504f
#define SHIFT2 86.5617f      // 60 * log2(e)
#define JSLICE 8
#define BN_ (B_ * N_)
#define NT_ 16               // j-tiles per block (512 j)

typedef _Float16 half_t;
typedef _Float16 v8h  __attribute__((ext_vector_type(8)));
typedef _Float16 v4h  __attribute__((ext_vector_type(4)));
typedef float    v16f __attribute__((ext_vector_type(16)));

#define GLDS16(g, l) __builtin_amdgcn_global_load_lds(                         \
    (const __attribute__((address_space(1))) void*)(g),                        \
    (__attribute__((address_space(3))) void*)(l), 16, 0, 0)

// --------------------------------------------- prep: transpose + old lambda
// grid (N/64, C/64, 9), block 256.  (R10 version)
// z in [0,8): fp32 [B][C][N] -> fp16 fragment-tiled
//   t16[b][tile=n/32][kb=c/16][lane][e], lane=((c>>3)&1)*32+(n&31), e=c&7;
//   src (z<4) additionally scaled by log2(e).
// z == 8: oldL/oldB = 1x1 conv on ref (b = blockIdx.y, n0 = blockIdx.x*64).
__global__ void k_prep(const float* __restrict__ src,
                       const float* __restrict__ ref,
                       const float* __restrict__ wl, const float* __restrict__ bl,
                       const float* __restrict__ wb, const float* __restrict__ bb,
                       half_t* __restrict__ s16, half_t* __restrict__ r16,
                       float* __restrict__ oldL, float* __restrict__ oldB) {
    if (blockIdx.z == 8) {
        int b  = blockIdx.y;
        int n0 = blockIdx.x * 64;
        int nl = threadIdx.x & 63;
        int cq = threadIdx.x >> 6;           // 0..3
        const float* p = ref + ((size_t)b * C_ + cq * 64) * N_ + n0 + nl;
        float aL = 0.f, aB = 0.f;
#pragma unroll 8
        for (int c = 0; c < 64; c++) {
            float v = p[(size_t)c * N_];
            aL += v * wl[cq * 64 + c];
            aB += v * wb[cq * 64 + c];
        }
        __shared__ float red[8][64];
        red[cq][nl]     = aL;
        red[4 + cq][nl] = aB;
        __syncthreads();
        if (threadIdx.x < 64) {
            int t = threadIdx.x;
            oldL[(size_t)b * N_ + n0 + t] =
                red[0][t] + red[1][t] + red[2][t] + red[3][t] + bl[0];
        } else if (threadIdx.x < 128) {
            int t = threadIdx.x - 64;
            oldB[(size_t)b * N_ + n0 + t] =
                red[4][t] + red[5][t] + red[6][t] + red[7][t] + bb[0];
        }
        return;
    }
    __shared__ float tile[64][65];
    int z  = blockIdx.z;
    int b  = z & 3;
    const float* in  = (z < B_) ? src : ref;
    half_t*      out = (z < B_) ? s16 : r16;
    float scale      = (z < B_) ? LOG2E : 1.0f;
    int c0 = blockIdx.y * 64;
    int n0 = blockIdx.x * 64;
    int tx = threadIdx.x & 15, ty = threadIdx.x >> 4;
#pragma unroll
    for (int q = 0; q < 4; q++) {
        int c = ty + q * 16;
        float4 v = *(const float4*)(in + ((size_t)b * C_ + c0 + c) * N_ + n0 + tx * 4);
        tile[c][tx * 4 + 0] = v.x;
        tile[c][tx * 4 + 1] = v.y;
        tile[c][tx * 4 + 2] = v.z;
        tile[c][tx * 4 + 3] = v.w;
    }
    __syncthreads();
    int r   = threadIdx.x & 31;
    int lhi = (threadIdx.x >> 5) & 1;
    int wv  = threadIdx.x >> 6;          // kb_local 0..3
#pragma unroll
    for (int nt = 0; nt < 2; nt++) {
        int nl = nt * 32 + r;
        v8h o;
#pragma unroll
        for (int e = 0; e < 8; e++)
            o[e] = (half_t)(tile[wv * 16 + lhi * 8 + e][nl] * scale);
        size_t tj = (size_t)(n0 >> 5) + nt;
        size_t kb = (size_t)(c0 >> 4) + wv;
        *(v8h*)(out + ((((size_t)b * 128 + tj) * 16 + kb) * 64 + (threadIdx.x & 63)) * 8) = o;
    }
}

// ------------------------------------------------------------------ flash
// grid 512 = B(4) x jslice(8) x iblock(16):
//   b = bid&3 (XCD spread), jslice = (bid>>2)&7, iblock = bid>>5.
// block = 512 thr = 8 waves; wave owns 32 i-rows (256 rows/block); the 16
// B-tiles (16KB each) staged once per block via global_load_lds into
// double-buffered LDS, shared by all 8 waves. Dual 8-deep MFMA chains.
__global__ __launch_bounds__(512, 2) void k_flash(
        const half_t* __restrict__ sT, const half_t* __restrict__ rT,
        const float* __restrict__ oldL, const float* __restrict__ oldB,
        float* __restrict__ part /* [JSLICE][3][B*N] */) {
    __shared__ half_t lds[2][8192];      // 2 x 16KB
    int bid    = blockIdx.x;
    int b      = bid & 3;
    int jslice = (bid >> 2) & (JSLICE - 1);
    int iblock = bid >> 5;
    int tid    = threadIdx.x;
    int wv     = tid >> 6;               // 0..7
    int lane   = tid & 63;
    int l31    = lane & 31, lhi = lane >> 5;
    int ti     = iblock * 8 + wv;        // 32-row A tile index
    int i0     = ti * 32;
    int j0     = jslice * (N_ / JSLICE); // 512 j per block
    int tj0    = j0 >> 5;

    // A fragments: one coalesced 1KB load per kb, held in VGPRs all kernel.
    const half_t* aP = sT + (((size_t)b * 128 + ti) * 16) * 512 + (size_t)lane * 8;
    v8h a[16];
#pragma unroll
    for (int kb = 0; kb < 16; kb++) a[kb] = *(const v8h*)(aP + (size_t)kb * 512);

    const half_t* bBase = rT + (((size_t)b * 128 + tj0) * 16) * 512;  // block-uniform
    const float*  oLp = oldL + (size_t)b * N_ + j0 + l31;
    const float*  oBp = oldB + (size_t)b * N_ + j0 + l31;

    float sp[16], sl[16], sb[16];
#pragma unroll
    for (int r = 0; r < 16; r++) { sp[r] = 0.f; sl[r] = 0.f; sb[r] = 0.f; }

    // Prologue: DMA tile 0 into buffer 0. Wave wv covers chunks {wv, wv+8}.
#pragma unroll
    for (int q = 0; q < 2; q++) {
        int chunk = q * 8 + wv;
        GLDS16(bBase + (size_t)chunk * 512 + (size_t)lane * 8,
               &lds[0][(size_t)chunk * 512]);
    }

    for (int jt = 0; jt < NT_; jt++) {
        __syncthreads();                       // drains DMA -> buf[jt&1] ready
        if (jt + 1 < NT_) {                    // DMA next tile into other buffer
            const half_t* g = bBase + (size_t)(jt + 1) * 8192;
#pragma unroll
            for (int q = 0; q < 2; q++) {
                int chunk = q * 8 + wv;
                GLDS16(g + (size_t)chunk * 512 + (size_t)lane * 8,
                       &lds[(jt + 1) & 1][(size_t)chunk * 512]);
            }
        }
        const half_t* bt = lds[jt & 1] + (size_t)lane * 8;
        // Two independent 8-deep MFMA chains (halve the acc-dependency path).
        v16f acc0, acc1;
#pragma unroll
        for (int r = 0; r < 16; r++) { acc0[r] = -SHIFT2; acc1[r] = 0.f; }
#pragma unroll
        for (int kb = 0; kb < 8; kb++) {
            acc0 = __builtin_amdgcn_mfma_f32_32x32x16_f16(
                a[kb],     *(const v8h*)(bt + (size_t)kb * 512),       acc0, 0, 0, 0);
            acc1 = __builtin_amdgcn_mfma_f32_32x32x16_f16(
                a[kb + 8], *(const v8h*)(bt + (size_t)(kb + 8) * 512), acc1, 0, 0, 0);
        }
        float lam = oLp[jt * 32], bet = oBp[jt * 32];
#pragma unroll
        for (int r = 0; r < 16; r++) {
            float p = __builtin_amdgcn_exp2f(acc0[r] + acc1[r]);
            sp[r] += p;
            sl[r] += p * lam;
            sb[r] += p * bet;
        }
    }

    float* pSP = part + ((size_t)jslice * 3 + 0) * BN_;
    float* pSL = part + ((size_t)jslice * 3 + 1) * BN_;
    float* pSB = part + ((size_t)jslice * 3 + 2) * BN_;
#pragma unroll
    for (int r = 0; r < 16; r++) {
        float tp = sp[r], tl = sl[r], tb = sb[r];
#pragma unroll
        for (int m = 1; m <= 16; m <<= 1) {
            tp += __shfl_xor(tp, m, 64);
            tl += __shfl_xor(tl, m, 64);
            tb += __shfl_xor(tb, m, 64);
        }
        if (l31 == 0) {
            // C/D layout: row = (reg&3) + 8*(reg>>2) + 4*(lane>>5)
            int row = (r & 3) + 8 * (r >> 2) + 4 * lhi;
            size_t ig = (size_t)b * N_ + i0 + row;
            pSP[ig] = tp; pSL[ig] = tl; pSB[ig] = tb;
        }
    }
}

// ------------------------- epilogue: combine partials + modulate (fused)
// grid (B, N/1024, C/16), block 256. Thread owns 4 consecutive pixels:
// newL/newB computed once into registers, then a 16-channel sweep with
// 4KB-contiguous float4 lines.
__global__ void k_post(const float* __restrict__ src,
                       const float* __restrict__ part,
                       float* __restrict__ out) {
    int b  = blockIdx.x;
    int n0 = blockIdx.y * 1024;
    int c0 = blockIdx.z * 16;
    int t  = threadIdx.x;
    size_t bn = (size_t)b * N_ + n0 + t * 4;
    float4 sp = {0.f, 0.f, 0.f, 0.f}, sl = sp, sb = sp;
#pragma unroll
    for (int s = 0; s < JSLICE; s++) {
        float4 p0 = *(const float4*)(part + ((size_t)s * 3 + 0) * BN_ + bn);
        float4 p1 = *(const float4*)(part + ((size_t)s * 3 + 1) * BN_ + bn);
        float4 p2 = *(const float4*)(part + ((size_t)s * 3 + 2) * BN_ + bn);
        sp.x += p0.x; sp.y += p0.y; sp.z += p0.z; sp.w += p0.w;
        sl.x += p1.x; sl.y += p1.y; sl.z += p1.z; sl.w += p1.w;
        sb.x += p2.x; sb.y += p2.y; sb.z += p2.z; sb.w += p2.w;
    }
    float4 L, T;
    L.x = sl.x / sp.x; L.y = sl.y / sp.y; L.z = sl.z / sp.z; L.w = sl.w / sp.w;
    T.x = sb.x / sp.x; T.y = sb.y / sp.y; T.z = sb.z / sp.z; T.w = sb.w / sp.w;
    const float* sp0 = src + ((size_t)b * C_ + c0) * N_ + n0 + t * 4;
    float*       op0 = out + ((size_t)b * C_ + c0) * N_ + n0 + t * 4;
#pragma unroll 4
    for (int c = 0; c < 16; c++) {
        float4 v = *(const float4*)(sp0 + (size_t)c * N_);
        float4 o;
        o.x = L.x * v.x + T.x;
        o.y = L.y * v.y + T.y;
        o.z = L.z * v.z + T.z;
        o.w = L.w * v.w + T.w;
        *(float4*)(op0 + (size_t)c * N_) = o;
    }
}

extern "C" void kernel_launch(void* const* d_in, const int* in_sizes, int n_in,
                              void* d_out, int out_size, void* d_ws, size_t ws_size,
                              hipStream_t stream) {
    const float* src = (const float*)d_in[0];
    const float* ref = (const float*)d_in[1];
    const float* wl  = (const float*)d_in[2];
    const float* bl  = (const float*)d_in[3];
    const float* wb  = (const float*)d_in[4];
    const float* bb  = (const float*)d_in[5];
    float* out = (float*)d_out;

    float* oldL = (float*)d_ws;
    float* oldB = oldL + BN_;
    float* part = oldB + BN_;
    size_t needF  = ((size_t)2 + 3 * JSLICE) * BN_ * sizeof(float);
    size_t need16 = (size_t)2 * B_ * N_ * C_ * sizeof(half_t);
    half_t* s16;
    if (ws_size >= needF + need16) s16 = (half_t*)((char*)d_ws + needF);
    else                           s16 = (half_t*)d_out;   // overwritten by k_post
    half_t* r16 = s16 + (size_t)B_ * N_ * C_;

    k_prep<<<dim3(N_ / 64, C_ / 64, 9), 256, 0, stream>>>(
        src, ref, wl, bl, wb, bb, s16, r16, oldL, oldB);
    k_flash<<<512, 512, 0, stream>>>(s16, r16, oldL, oldB, part);
    k_post<<<dim3(B_, N_ / 1024, C_ / 16), 256, 0, stream>>>(src, part, out);
}